// Round 7
// baseline (184.239 us; speedup 1.0000x reference)
//
#include <hip/hip_runtime.h>
#include <hip/hip_cooperative_groups.h>

namespace cg = cooperative_groups;

// YOLO-v1 style loss on MI355X (gfx950).
// Inputs: d_in[0] = output (BATCH*S*S*30 fp32), d_in[1] = target (same).
// Outputs: d_out[0..2] = (loss, sum_iou, acc) as fp32.
//
// R8 post-mortem / ceiling analysis: five structurally different
// schedules (barrier-staged, direct, persistent counted-vmcnt, one-shot,
// wave-private zero-barrier) all plateau at 9-12.5 GB/s/CU read
// (~3.2 TB/s chip). Little's law shows large schedule slack in R5/R8 ->
// this is the read-PATH throughput ceiling (~400 GB/s/XCD L2-miss/fabric),
// not a schedule artifact. m13's "6.29 TB/s copy" = 3.15r+3.15w and the
// 6.5 TB/s pure-write fills corroborate an asymmetric read lane. Input is
// read-once (no reuse; 12MB/XCD > 4MB L2) -> 96.3MB / 3.2TB/s ~= 30us is
// the loss floor and R5/R8 are at it.
// R9: the only remaining controllable term is the finalize launch
// (~3-4us). Fuse it via ONE cooperative launch: R8's wave-private
// pipeline unchanged, partial stores, __threadfence + grid.sync(),
// block 0 reduces 256x8 and writes d_out. GRID=256 = 1 block/CU ->
// co-residency guaranteed.

#define NACC 8
#define WCELLS 64                      // cells per wave-tile
#define WFLOATS (WCELLS * 30)          // 1920 floats = 7680 B per array
#define WCHUNKS (WFLOATS / 4)          // 480 float4 per array
#define GRID 256                       // 1 block/CU, 4 waves each
#define NWAVES (GRID * 4)              // 1024 wave pipelines

__device__ __forceinline__ float wave_reduce_sum(float v) {
    #pragma unroll
    for (int off = 32; off > 0; off >>= 1)
        v += __shfl_down(v, off, 64);
    return v;
}

__device__ __forceinline__ void gld16(const float4* g, float4* l) {
    __builtin_amdgcn_global_load_lds(
        (const __attribute__((address_space(1))) void*)g,
        (__attribute__((address_space(3))) void*)l, 16, 0, 0);
}

// Per-cell loss contributions; o/t are 30 floats with compile-time indices.
__device__ __forceinline__ void cell_loss(const float* __restrict__ o,
                                          const float* __restrict__ t,
                                          float v[NACC]) {
    const float m = (t[4] > 0.f) ? 1.f : 0.f;

    const float txc = t[0] / 7.f, tyc = t[1] / 7.f;
    const float tx0 = txc - 0.5f * t[2], ty0 = tyc - 0.5f * t[3];
    const float tx1 = txc + 0.5f * t[2], ty1 = tyc + 0.5f * t[3];
    const float at  = (tx1 - tx0) * (ty1 - ty0);

    float iou[2];
    #pragma unroll
    for (int b = 0; b < 2; b++) {
        const float bx = o[5 * b + 0], by = o[5 * b + 1];
        const float bw = o[5 * b + 2], bh = o[5 * b + 3];
        const float xc = bx / 7.f, yc = by / 7.f;
        const float x0 = xc - 0.5f * bw, y0 = yc - 0.5f * bh;
        const float x1 = xc + 0.5f * bw, y1 = yc + 0.5f * bh;
        const float ap = (x1 - x0) * (y1 - y0);
        const float wi = fmaxf(fminf(x1, tx1) - fmaxf(x0, tx0), 0.f);
        const float hi = fmaxf(fminf(y1, ty1) - fmaxf(y0, ty0), 0.f);
        const float inter = wi * hi;
        iou[b] = inter / (ap + at - inter);
    }

    // first-max tie-break: box 1 responsible only if STRICTLY greater
    const bool  r1      = iou[1] > iou[0];
    const float max_iou = fmaxf(iou[0], iou[1]);
    const float min_iou = fminf(iou[0], iou[1]);
    const float rb0 = r1 ? o[5] : o[0];
    const float rb1 = r1 ? o[6] : o[1];
    const float rb2 = r1 ? o[7] : o[2];
    const float rb3 = r1 ? o[8] : o[3];
    const float rb4 = r1 ? o[9] : o[4];
    const float nb4 = r1 ? o[4] : o[9];

    {
        const float dx = rb0 - t[0];
        const float dy = rb1 - t[1];
        const float dw = sqrtf(rb2) - sqrtf(t[2]);
        const float dh = sqrtf(rb3) - sqrtf(t[3]);
        v[1] += m * (dx * dx + dy * dy + dw * dw + dh * dh);
    }
    {
        const float d = rb4 - max_iou;
        v[2] += m * d * d;
    }
    v[3] += m * nb4 * nb4;
    {
        const float d0 = o[4] - t[4];
        const float d1 = o[9] - t[9];
        v[4] += (1.f - m) * (d0 * d0 + d1 * d1);
    }

    float cls_sum = 0.f;
    int   oarg = 0, targ = 0;
    float obest = o[10], tbest = t[10];
    #pragma unroll
    for (int c = 0; c < 20; c++) {
        const float oc = o[10 + c], tc = t[10 + c];
        const float d = oc - tc;
        cls_sum += d * d;
        if (oc > obest) { obest = oc; oarg = c; }
        if (tc > tbest) { tbest = tc; targ = c; }
    }
    v[5] += m * cls_sum;
    v[6] += m * min_iou;
    v[7] += (m > 0.f && oarg == targ) ? 1.f : 0.f;
    v[0] += m;
}

__global__ __launch_bounds__(256) void yolo_loss_fused(
        const float* __restrict__ out,
        const float* __restrict__ tgt,
        float* __restrict__ partials,
        float* __restrict__ res, int N) {
    // [wave][buf][A/B][chunk]: 4*2*2*480*16B = 122880 B, wave-private slices
    __shared__ float4 lds4[4][2][2][WCHUNKS];
    __shared__ float sred[4][NACC];

    const int tid  = threadIdx.x;
    const int lane = tid & 63;
    const int wid  = tid >> 6;
    const int numTiles = N / WCELLS;
    const int gw = blockIdx.x * 4 + wid;   // global wave id, stride NWAVES

    float v[NACC];
    #pragma unroll
    for (int k = 0; k < NACC; k++) v[k] = 0.f;

    // 15 gld_lds per lane per tile, wave-uniform (round 7 split by lane):
    auto stage = [&](int buf, int tile) {
        const float4* gA = (const float4*)(out + (size_t)tile * WFLOATS);
        const float4* gB = (const float4*)(tgt + (size_t)tile * WFLOATS);
        float4* lA = &lds4[wid][buf][0][0];
        float4* lB = &lds4[wid][buf][1][0];
        #pragma unroll
        for (int r = 0; r < 7; r++) {
            const int c = r * 64 + lane;
            gld16(gA + c, lA + c);
        }
        if (lane < 32) gld16(gA + 448 + lane, lA + 448 + lane);
        else           gld16(gB + (lane - 32), lB + (lane - 32));
        #pragma unroll
        for (int r = 0; r < 7; r++) {
            const int c = 32 + r * 64 + lane;
            gld16(gB + c, lB + c);
        }
    };

    auto compute = [&](int buf) {
        float o[30], t[30];
        const float2* a2 =
            (const float2*)((const float*)&lds4[wid][buf][0][0] + lane * 30);
        const float2* b2 =
            (const float2*)((const float*)&lds4[wid][buf][1][0] + lane * 30);
        #pragma unroll
        for (int k = 0; k < 15; k++) {
            const float2 xa = a2[k];
            o[2 * k] = xa.x; o[2 * k + 1] = xa.y;
            const float2 xb = b2[k];
            t[2 * k] = xb.x; t[2 * k + 1] = xb.y;
        }
        cell_loss(o, t, v);
    };

    int t = gw;
    if (t < numTiles) {
        stage(0, t);
        int cur = 0;
        for (;;) {
            const int tn = t + NWAVES;
            const bool more = (tn < numTiles);
            if (more) {
                stage(cur ^ 1, tn);
                // current tile's 15 loads retire; next tile's 15 in flight
                asm volatile("s_waitcnt vmcnt(15)" ::: "memory");
            } else {
                asm volatile("s_waitcnt vmcnt(0)" ::: "memory");
            }
            compute(cur);
            if (!more) break;
            cur ^= 1;
            t = tn;
        }
    }

    // tail cells (N % WCELLS): block 0 wave 0, direct loads (empty for 401408)
    const int rem = N - numTiles * WCELLS;
    if (rem > 0 && blockIdx.x == 0 && wid == 0 && lane < rem) {
        float o[30], tt[30];
        const size_t cb = (size_t)(numTiles * WCELLS + lane) * 30;
        const float2* a2 = (const float2*)(out + cb);
        const float2* b2 = (const float2*)(tgt + cb);
        #pragma unroll
        for (int k = 0; k < 15; k++) {
            const float2 xa = a2[k];
            o[2 * k] = xa.x; o[2 * k + 1] = xa.y;
            const float2 xb = b2[k];
            tt[2 * k] = xb.x; tt[2 * k + 1] = xb.y;
        }
        cell_loss(o, tt, v);
    }

    // block reduce -> one partial row per block
    #pragma unroll
    for (int k = 0; k < NACC; k++) v[k] = wave_reduce_sum(v[k]);
    if (lane == 0) {
        #pragma unroll
        for (int k = 0; k < NACC; k++) sred[wid][k] = v[k];
    }
    __syncthreads();
    if (tid < NACC) {
        const int k = tid;
        partials[(size_t)blockIdx.x * NACC + k] =
            sred[0][k] + sred[1][k] + sred[2][k] + sred[3][k];
    }

    // fused finalize: device-scope visibility, grid-wide sync, block 0 reduces
    __threadfence();
    cg::this_grid().sync();

    if (blockIdx.x == 0) {
        float w[NACC];
        #pragma unroll
        for (int k = 0; k < NACC; k++) w[k] = 0.f;
        // 256 rows, 256 threads: thread tid owns row tid (8 KB total)
        #pragma unroll
        for (int k = 0; k < NACC; k++)
            w[k] = partials[(size_t)tid * NACC + k];
        #pragma unroll
        for (int k = 0; k < NACC; k++) w[k] = wave_reduce_sum(w[k]);
        __syncthreads();   // sred reuse: all waves past previous reads
        if (lane == 0) {
            #pragma unroll
            for (int k = 0; k < NACC; k++) sred[wid][k] = w[k];
        }
        __syncthreads();
        if (tid == 0) {
            float acc[NACC];
            #pragma unroll
            for (int k = 0; k < NACC; k++)
                acc[k] = sred[0][k] + sred[1][k] + sred[2][k] + sred[3][k];
            const float n_obj   = acc[0];
            const float n_noobj = (float)N - n_obj;
            const float contain     = acc[1] / (2.f * n_obj);
            const float obj_loss    = acc[2] / n_obj;
            const float not_contain = acc[3] / n_obj;
            const float noobj_loss  = acc[4] / (2.f * n_noobj);
            const float class_loss  = acc[5] / (n_obj * 20.f);
            res[0] = 5.f * contain + obj_loss
                   + 0.5f * (noobj_loss + not_contain) + class_loss;
            res[1] = acc[6];
            res[2] = acc[7];
        }
    }
}

extern "C" void kernel_launch(void* const* d_in, const int* in_sizes, int n_in,
                              void* d_out, int out_size, void* d_ws, size_t ws_size,
                              hipStream_t stream) {
    const float* out_p = (const float*)d_in[0];
    const float* tgt_p = (const float*)d_in[1];
    float* ws  = (float*)d_ws;   // GRID*NACC partial sums
    float* res = (float*)d_out;
    int N = in_sizes[0] / 30;    // 8192*7*7 = 401408 cells

    void* args[] = {(void*)&out_p, (void*)&tgt_p, (void*)&ws,
                    (void*)&res, (void*)&N};
    hipLaunchCooperativeKernel((const void*)yolo_loss_fused,
                               dim3(GRID), dim3(256), args, 0, stream);
}

// Round 8
// 144.420 us; speedup vs baseline: 1.2757x; 1.2757x over previous
//
#include <hip/hip_runtime.h>

// YOLO-v1 style loss on MI355X (gfx950).
// Inputs: d_in[0] = output (BATCH*S*S*30 fp32), d_in[1] = target (same).
// Outputs: d_out[0..2] = (loss, sum_iou, acc) as fp32.
//
// R9 post-mortem: cooperative-launch fusion = 2.5x slower kernel (78us
// even L3-warm, VGPR 132, 452K bank conflicts) -- coop launch perturbs
// codegen/scheduling wholesale. Reverted.
// R7 re-read: the plain-load staging test "failed" only because the
// compiler targeted ~7 waves/SIMD (VGPR cap 68) and spilled the 64-VGPR
// staging buffer to scratch (WRITE_SIZE 94MB) -- while LDS caps occupancy
// at 5 blocks/CU regardless. The gld_lds-queue theory (all pipelined
// gld_lds variants cap at ~12.5 GB/s/CU; plain-VMEM fills hit 6.5 TB/s)
// was never actually tested.
// R10: R7 re-run with __launch_bounds__(128, 2) -> VGPR cap 256, no
// spill. One-shot 128-cell/128-thread blocks, 30.7KB LDS, 5 blocks/CU.
// Stage = 15 plain global_load_dwordx4 per lane issued back-to-back
// (deep VMEM queue, 15KB in flight per wave) -> ds_write_b128 -> one
// __syncthreads -> compute. Single variable vs R6: staging primitive.

#define NACC 8
#define CELLS 128
#define TPB 128
#define TILE_FLOATS (CELLS * 30)        // 3840 floats = 15360 B per array
#define TILE_CHUNKS (TILE_FLOATS / 4)   // 960 float4 chunks per array

__device__ __forceinline__ float wave_reduce_sum(float v) {
    #pragma unroll
    for (int off = 32; off > 0; off >>= 1)
        v += __shfl_down(v, off, 64);
    return v;
}

// Per-cell loss contributions; o/t are 30 floats with compile-time indices.
__device__ __forceinline__ void cell_loss(const float* __restrict__ o,
                                          const float* __restrict__ t,
                                          float v[NACC]) {
    const float m = (t[4] > 0.f) ? 1.f : 0.f;

    const float txc = t[0] / 7.f, tyc = t[1] / 7.f;
    const float tx0 = txc - 0.5f * t[2], ty0 = tyc - 0.5f * t[3];
    const float tx1 = txc + 0.5f * t[2], ty1 = tyc + 0.5f * t[3];
    const float at  = (tx1 - tx0) * (ty1 - ty0);

    float iou[2];
    #pragma unroll
    for (int b = 0; b < 2; b++) {
        const float bx = o[5 * b + 0], by = o[5 * b + 1];
        const float bw = o[5 * b + 2], bh = o[5 * b + 3];
        const float xc = bx / 7.f, yc = by / 7.f;
        const float x0 = xc - 0.5f * bw, y0 = yc - 0.5f * bh;
        const float x1 = xc + 0.5f * bw, y1 = yc + 0.5f * bh;
        const float ap = (x1 - x0) * (y1 - y0);
        const float wi = fmaxf(fminf(x1, tx1) - fmaxf(x0, tx0), 0.f);
        const float hi = fmaxf(fminf(y1, ty1) - fmaxf(y0, ty0), 0.f);
        const float inter = wi * hi;
        iou[b] = inter / (ap + at - inter);
    }

    // first-max tie-break: box 1 responsible only if STRICTLY greater
    const bool  r1      = iou[1] > iou[0];
    const float max_iou = fmaxf(iou[0], iou[1]);
    const float min_iou = fminf(iou[0], iou[1]);
    const float rb0 = r1 ? o[5] : o[0];
    const float rb1 = r1 ? o[6] : o[1];
    const float rb2 = r1 ? o[7] : o[2];
    const float rb3 = r1 ? o[8] : o[3];
    const float rb4 = r1 ? o[9] : o[4];
    const float nb4 = r1 ? o[4] : o[9];

    {
        const float dx = rb0 - t[0];
        const float dy = rb1 - t[1];
        const float dw = sqrtf(rb2) - sqrtf(t[2]);
        const float dh = sqrtf(rb3) - sqrtf(t[3]);
        v[1] += m * (dx * dx + dy * dy + dw * dw + dh * dh);
    }
    {
        const float d = rb4 - max_iou;
        v[2] += m * d * d;
    }
    v[3] += m * nb4 * nb4;
    {
        const float d0 = o[4] - t[4];
        const float d1 = o[9] - t[9];
        v[4] += (1.f - m) * (d0 * d0 + d1 * d1);
    }

    float cls_sum = 0.f;
    int   oarg = 0, targ = 0;
    float obest = o[10], tbest = t[10];
    #pragma unroll
    for (int c = 0; c < 20; c++) {
        const float oc = o[10 + c], tc = t[10 + c];
        const float d = oc - tc;
        cls_sum += d * d;
        if (oc > obest) { obest = oc; oarg = c; }
        if (tc > tbest) { tbest = tc; targ = c; }
    }
    v[5] += m * cls_sum;
    v[6] += m * min_iou;
    v[7] += (m > 0.f && oarg == targ) ? 1.f : 0.f;
    v[0] += m;
}

// 2nd launch_bounds arg = min waves/EU: 2 -> VGPR cap 256, NO SPILL.
// (LDS caps occupancy at 5 blocks/CU = 2.5 waves/SIMD anyway; the default
// heuristic's 7-waves/SIMD VGPR target is what sank R7.)
__global__ __launch_bounds__(TPB, 2) void yolo_loss_kernel(
        const float* __restrict__ out,
        const float* __restrict__ tgt,
        float* __restrict__ partials, int N) {
    __shared__ float sA[TILE_FLOATS];   // 15360 B
    __shared__ float sB[TILE_FLOATS];   // 15360 B
    __shared__ float sred[2][NACC];

    const int tid   = threadIdx.x;
    const int tile0 = blockIdx.x * CELLS;
    const int cells = min(CELLS, N - tile0);

    float v[NACC];
    #pragma unroll
    for (int k = 0; k < NACC; k++) v[k] = 0.f;

    if (cells == CELLS) {
        // reg-stage: issue all 15 (16 slots, j==7 half-wave) plain float4
        // loads back-to-back -> deep VMEM queue; then ds_write_b128 all.
        const float4* gA = (const float4*)(out + (size_t)tile0 * 30);
        const float4* gB = (const float4*)(tgt + (size_t)tile0 * 30);
        float4* lA = (float4*)sA;
        float4* lB = (float4*)sB;
        float4 ra[8], rb[8];
        #pragma unroll
        for (int j = 0; j < 8; j++) {
            const int c = j * TPB + tid;
            if (j < 7 || c < TILE_CHUNKS) ra[j] = gA[c];
        }
        #pragma unroll
        for (int j = 0; j < 8; j++) {
            const int c = j * TPB + tid;
            if (j < 7 || c < TILE_CHUNKS) rb[j] = gB[c];
        }
        #pragma unroll
        for (int j = 0; j < 8; j++) {
            const int c = j * TPB + tid;
            if (j < 7 || c < TILE_CHUNKS) lA[c] = ra[j];
        }
        #pragma unroll
        for (int j = 0; j < 8; j++) {
            const int c = j * TPB + tid;
            if (j < 7 || c < TILE_CHUNKS) lB[c] = rb[j];
        }
        __syncthreads();

        float o[30], t[30];
        const float2* a2 = (const float2*)(sA + tid * 30);
        const float2* b2 = (const float2*)(sB + tid * 30);
        #pragma unroll
        for (int k = 0; k < 15; k++) {
            const float2 xa = a2[k];
            o[2 * k] = xa.x; o[2 * k + 1] = xa.y;
            const float2 xb = b2[k];
            t[2 * k] = xb.x; t[2 * k + 1] = xb.y;
        }
        cell_loss(o, t, v);
    } else if (tid < cells) {
        // tail tile: direct loads (uncoalesced but tiny: <128 cells once)
        float o[30], t[30];
        const size_t cb = (size_t)(tile0 + tid) * 30;
        const float2* a2 = (const float2*)(out + cb);
        const float2* b2 = (const float2*)(tgt + cb);
        #pragma unroll
        for (int k = 0; k < 15; k++) {
            const float2 xa = a2[k];
            o[2 * k] = xa.x; o[2 * k + 1] = xa.y;
            const float2 xb = b2[k];
            t[2 * k] = xb.x; t[2 * k + 1] = xb.y;
        }
        cell_loss(o, t, v);
    }

    // 2-wave block reduce -> one plain store set per block (no atomics)
    const int lane = tid & 63;
    const int wid  = tid >> 6;
    #pragma unroll
    for (int k = 0; k < NACC; k++) v[k] = wave_reduce_sum(v[k]);
    if (cells != CELLS) __syncthreads();  // tail path: uniform, harmless
    if (lane == 0) {
        #pragma unroll
        for (int k = 0; k < NACC; k++) sred[wid][k] = v[k];
    }
    __syncthreads();
    if (tid < NACC) {
        const int k = tid;
        partials[(size_t)blockIdx.x * NACC + k] = sred[0][k] + sred[1][k];
    }
}

__global__ __launch_bounds__(256) void yolo_finalize_kernel(
        const float* __restrict__ partials,
        float* __restrict__ res, int N, int rows) {
    __shared__ float sred[4][NACC];
    float v[NACC];
    #pragma unroll
    for (int k = 0; k < NACC; k++) v[k] = 0.f;

    for (int b = threadIdx.x; b < rows; b += 256) {
        #pragma unroll
        for (int k = 0; k < NACC; k++)
            v[k] += partials[(size_t)b * NACC + k];
    }

    const int lane = threadIdx.x & 63;
    const int wid  = threadIdx.x >> 6;
    #pragma unroll
    for (int k = 0; k < NACC; k++) v[k] = wave_reduce_sum(v[k]);
    if (lane == 0) {
        #pragma unroll
        for (int k = 0; k < NACC; k++) sred[wid][k] = v[k];
    }
    __syncthreads();
    if (threadIdx.x == 0) {
        float acc[NACC];
        #pragma unroll
        for (int k = 0; k < NACC; k++)
            acc[k] = sred[0][k] + sred[1][k] + sred[2][k] + sred[3][k];
        const float n_obj   = acc[0];
        const float n_noobj = (float)N - n_obj;
        const float contain     = acc[1] / (2.f * n_obj);
        const float obj_loss    = acc[2] / n_obj;
        const float not_contain = acc[3] / n_obj;
        const float noobj_loss  = acc[4] / (2.f * n_noobj);
        const float class_loss  = acc[5] / (n_obj * 20.f);
        res[0] = 5.f * contain + obj_loss
               + 0.5f * (noobj_loss + not_contain) + class_loss;
        res[1] = acc[6];
        res[2] = acc[7];
    }
}

extern "C" void kernel_launch(void* const* d_in, const int* in_sizes, int n_in,
                              void* d_out, int out_size, void* d_ws, size_t ws_size,
                              hipStream_t stream) {
    const float* out_p = (const float*)d_in[0];
    const float* tgt_p = (const float*)d_in[1];
    float* ws  = (float*)d_ws;   // blocks*NACC partial sums
    float* res = (float*)d_out;
    const int N = in_sizes[0] / 30;        // 8192*7*7 = 401408 cells
    int blocks = (N + CELLS - 1) / CELLS;  // 3136 for N=401408
    if (blocks < 1) blocks = 1;

    yolo_loss_kernel<<<blocks, TPB, 0, stream>>>(out_p, tgt_p, ws, N);
    yolo_finalize_kernel<<<1, 256, 0, stream>>>(ws, res, N, blocks);
}

// Round 9
// 114.647 us; speedup vs baseline: 1.6070x; 1.2597x over previous
//
#include <hip/hip_runtime.h>

// YOLO-v1 style loss on MI355X (gfx950).
// Inputs: d_in[0] = output (BATCH*S*S*30 fp32), d_in[1] = target (same).
// Outputs: d_out[0..2] = (loss, sum_iou, acc) as fp32.
//
// R10 post-mortem: counters byte-identical to R7 (VGPR 68, WRITE_SIZE
// 94178 KB = exactly 240 B/thread scratch round-trip). launch_bounds(,2)
// changed nothing -> the spill is NOT occupancy-driven: the predicated
// j==7 element of ra[8]/rb[8] defeats SROA, and an unsplittable array
// goes to scratch regardless of VGPR budget. The gld_lds-queue theory
// (all gld_lds pipelines cap ~12.5 GB/s/CU read; plain-VMEM path proven
// to 6.5 TB/s on writes) has therefore STILL never been tested.
// R11: spill-proof reg-stage. 15 NAMED float4 scalars per thread, zero
// conditionals: wave-uniform split of the fractional round -- wave 0
// stages A[0..512) (8 rounds) + B[0..448) (7 rounds); wave 1 stages
// B[448..960) (8 rounds) + A[512..960) (7 rounds). All 15 loads issue
// before any ds_write (240 B/lane in flight). One-shot 128-cell blocks,
// 30.7 KB LDS, 5 blocks/CU. Validity check: WRITE_SIZE must drop to
// ~0.1 MB. Single variable vs R6: staging primitive (plain VMEM).

#define NACC 8
#define CELLS 128
#define TPB 128
#define TILE_FLOATS (CELLS * 30)        // 3840 floats = 15360 B per array

__device__ __forceinline__ float wave_reduce_sum(float v) {
    #pragma unroll
    for (int off = 32; off > 0; off >>= 1)
        v += __shfl_down(v, off, 64);
    return v;
}

// Stage 8 wave-rounds gx->lx and 7 wave-rounds gy->ly through named
// scalars (no arrays, no conditionals -> SROA-proof, no scratch).
__device__ __forceinline__ void stage15(const float4* __restrict__ gx,
                                        float4* lx,
                                        const float4* __restrict__ gy,
                                        float4* ly, int lane) {
    const float4 x0 = gx[lane];
    const float4 x1 = gx[64 + lane];
    const float4 x2 = gx[128 + lane];
    const float4 x3 = gx[192 + lane];
    const float4 x4 = gx[256 + lane];
    const float4 x5 = gx[320 + lane];
    const float4 x6 = gx[384 + lane];
    const float4 x7 = gx[448 + lane];
    const float4 y0 = gy[lane];
    const float4 y1 = gy[64 + lane];
    const float4 y2 = gy[128 + lane];
    const float4 y3 = gy[192 + lane];
    const float4 y4 = gy[256 + lane];
    const float4 y5 = gy[320 + lane];
    const float4 y6 = gy[384 + lane];
    lx[lane]       = x0;
    lx[64 + lane]  = x1;
    lx[128 + lane] = x2;
    lx[192 + lane] = x3;
    lx[256 + lane] = x4;
    lx[320 + lane] = x5;
    lx[384 + lane] = x6;
    lx[448 + lane] = x7;
    ly[lane]       = y0;
    ly[64 + lane]  = y1;
    ly[128 + lane] = y2;
    ly[192 + lane] = y3;
    ly[256 + lane] = y4;
    ly[320 + lane] = y5;
    ly[384 + lane] = y6;
}

// Per-cell loss contributions; o/t are 30 floats with compile-time indices.
__device__ __forceinline__ void cell_loss(const float* __restrict__ o,
                                          const float* __restrict__ t,
                                          float v[NACC]) {
    const float m = (t[4] > 0.f) ? 1.f : 0.f;

    const float txc = t[0] / 7.f, tyc = t[1] / 7.f;
    const float tx0 = txc - 0.5f * t[2], ty0 = tyc - 0.5f * t[3];
    const float tx1 = txc + 0.5f * t[2], ty1 = tyc + 0.5f * t[3];
    const float at  = (tx1 - tx0) * (ty1 - ty0);

    float iou[2];
    #pragma unroll
    for (int b = 0; b < 2; b++) {
        const float bx = o[5 * b + 0], by = o[5 * b + 1];
        const float bw = o[5 * b + 2], bh = o[5 * b + 3];
        const float xc = bx / 7.f, yc = by / 7.f;
        const float x0 = xc - 0.5f * bw, y0 = yc - 0.5f * bh;
        const float x1 = xc + 0.5f * bw, y1 = yc + 0.5f * bh;
        const float ap = (x1 - x0) * (y1 - y0);
        const float wi = fmaxf(fminf(x1, tx1) - fmaxf(x0, tx0), 0.f);
        const float hi = fmaxf(fminf(y1, ty1) - fmaxf(y0, ty0), 0.f);
        const float inter = wi * hi;
        iou[b] = inter / (ap + at - inter);
    }

    // first-max tie-break: box 1 responsible only if STRICTLY greater
    const bool  r1      = iou[1] > iou[0];
    const float max_iou = fmaxf(iou[0], iou[1]);
    const float min_iou = fminf(iou[0], iou[1]);
    const float rb0 = r1 ? o[5] : o[0];
    const float rb1 = r1 ? o[6] : o[1];
    const float rb2 = r1 ? o[7] : o[2];
    const float rb3 = r1 ? o[8] : o[3];
    const float rb4 = r1 ? o[9] : o[4];
    const float nb4 = r1 ? o[4] : o[9];

    {
        const float dx = rb0 - t[0];
        const float dy = rb1 - t[1];
        const float dw = sqrtf(rb2) - sqrtf(t[2]);
        const float dh = sqrtf(rb3) - sqrtf(t[3]);
        v[1] += m * (dx * dx + dy * dy + dw * dw + dh * dh);
    }
    {
        const float d = rb4 - max_iou;
        v[2] += m * d * d;
    }
    v[3] += m * nb4 * nb4;
    {
        const float d0 = o[4] - t[4];
        const float d1 = o[9] - t[9];
        v[4] += (1.f - m) * (d0 * d0 + d1 * d1);
    }

    float cls_sum = 0.f;
    int   oarg = 0, targ = 0;
    float obest = o[10], tbest = t[10];
    #pragma unroll
    for (int c = 0; c < 20; c++) {
        const float oc = o[10 + c], tc = t[10 + c];
        const float d = oc - tc;
        cls_sum += d * d;
        if (oc > obest) { obest = oc; oarg = c; }
        if (tc > tbest) { tbest = tc; targ = c; }
    }
    v[5] += m * cls_sum;
    v[6] += m * min_iou;
    v[7] += (m > 0.f && oarg == targ) ? 1.f : 0.f;
    v[0] += m;
}

__global__ __launch_bounds__(TPB, 2) void yolo_loss_kernel(
        const float* __restrict__ out,
        const float* __restrict__ tgt,
        float* __restrict__ partials, int N) {
    __shared__ float sA[TILE_FLOATS];   // 15360 B
    __shared__ float sB[TILE_FLOATS];   // 15360 B
    __shared__ float sred[2][NACC];

    const int tid   = threadIdx.x;
    const int lane  = tid & 63;
    const int wid   = tid >> 6;
    const int tile0 = blockIdx.x * CELLS;
    const int cells = min(CELLS, N - tile0);

    float v[NACC];
    #pragma unroll
    for (int k = 0; k < NACC; k++) v[k] = 0.f;

    if (cells == CELLS) {
        const float4* gA = (const float4*)(out + (size_t)tile0 * 30);
        const float4* gB = (const float4*)(tgt + (size_t)tile0 * 30);
        float4* lA = (float4*)sA;
        float4* lB = (float4*)sB;
        // wave-uniform split of the 960+960 chunks, 15 per thread, no
        // conditionals inside:
        if (wid == 0) stage15(gA,       lA,       gB,       lB,       lane);
        else          stage15(gB + 448, lB + 448, gA + 512, lA + 512, lane);
        __syncthreads();

        float o[30], t[30];
        const float2* a2 = (const float2*)(sA + tid * 30);
        const float2* b2 = (const float2*)(sB + tid * 30);
        #pragma unroll
        for (int k = 0; k < 15; k++) {
            const float2 xa = a2[k];
            o[2 * k] = xa.x; o[2 * k + 1] = xa.y;
            const float2 xb = b2[k];
            t[2 * k] = xb.x; t[2 * k + 1] = xb.y;
        }
        cell_loss(o, t, v);
    } else if (tid < cells) {
        // tail tile: direct loads (uncoalesced but tiny: <128 cells once)
        float o[30], t[30];
        const size_t cb = (size_t)(tile0 + tid) * 30;
        const float2* a2 = (const float2*)(out + cb);
        const float2* b2 = (const float2*)(tgt + cb);
        #pragma unroll
        for (int k = 0; k < 15; k++) {
            const float2 xa = a2[k];
            o[2 * k] = xa.x; o[2 * k + 1] = xa.y;
            const float2 xb = b2[k];
            t[2 * k] = xb.x; t[2 * k + 1] = xb.y;
        }
        cell_loss(o, t, v);
    }

    // 2-wave block reduce -> one plain store set per block (no atomics)
    #pragma unroll
    for (int k = 0; k < NACC; k++) v[k] = wave_reduce_sum(v[k]);
    if (cells != CELLS) __syncthreads();  // tail path: uniform, harmless
    if (lane == 0) {
        #pragma unroll
        for (int k = 0; k < NACC; k++) sred[wid][k] = v[k];
    }
    __syncthreads();
    if (tid < NACC) {
        const int k = tid;
        partials[(size_t)blockIdx.x * NACC + k] = sred[0][k] + sred[1][k];
    }
}

__global__ __launch_bounds__(256) void yolo_finalize_kernel(
        const float* __restrict__ partials,
        float* __restrict__ res, int N, int rows) {
    __shared__ float sred[4][NACC];
    float v[NACC];
    #pragma unroll
    for (int k = 0; k < NACC; k++) v[k] = 0.f;

    for (int b = threadIdx.x; b < rows; b += 256) {
        #pragma unroll
        for (int k = 0; k < NACC; k++)
            v[k] += partials[(size_t)b * NACC + k];
    }

    const int lane = threadIdx.x & 63;
    const int wid  = threadIdx.x >> 6;
    #pragma unroll
    for (int k = 0; k < NACC; k++) v[k] = wave_reduce_sum(v[k]);
    if (lane == 0) {
        #pragma unroll
        for (int k = 0; k < NACC; k++) sred[wid][k] = v[k];
    }
    __syncthreads();
    if (threadIdx.x == 0) {
        float acc[NACC];
        #pragma unroll
        for (int k = 0; k < NACC; k++)
            acc[k] = sred[0][k] + sred[1][k] + sred[2][k] + sred[3][k];
        const float n_obj   = acc[0];
        const float n_noobj = (float)N - n_obj;
        const float contain     = acc[1] / (2.f * n_obj);
        const float obj_loss    = acc[2] / n_obj;
        const float not_contain = acc[3] / n_obj;
        const float noobj_loss  = acc[4] / (2.f * n_noobj);
        const float class_loss  = acc[5] / (n_obj * 20.f);
        res[0] = 5.f * contain + obj_loss
               + 0.5f * (noobj_loss + not_contain) + class_loss;
        res[1] = acc[6];
        res[2] = acc[7];
    }
}

extern "C" void kernel_launch(void* const* d_in, const int* in_sizes, int n_in,
                              void* d_out, int out_size, void* d_ws, size_t ws_size,
                              hipStream_t stream) {
    const float* out_p = (const float*)d_in[0];
    const float* tgt_p = (const float*)d_in[1];
    float* ws  = (float*)d_ws;   // blocks*NACC partial sums
    float* res = (float*)d_out;
    const int N = in_sizes[0] / 30;        // 8192*7*7 = 401408 cells
    int blocks = (N + CELLS - 1) / CELLS;  // 3136 for N=401408
    if (blocks < 1) blocks = 1;

    yolo_loss_kernel<<<blocks, TPB, 0, stream>>>(out_p, tgt_p, ws, N);
    yolo_finalize_kernel<<<1, 256, 0, stream>>>(ws, res, N, blocks);
}